// Round 7
// baseline (381.947 us; speedup 1.0000x reference)
//
#include <hip/hip_runtime.h>

// Correlation: out[b,(di+4)*9+(dj+4),i,j] = (1/128) * sum_c f1[b,c,i,j]*f2[b,c,i+di,j+dj]
// B=8 C=128 H=128 W=256, di,dj in [-4,4], f2 zero-padded.
//
// v10 = v8 (last PASSING kernel: async LDS ring, 160us, FETCH=compulsory 132MB,
// VALUBusy 46%) + exactly ONE change, hardened:
//  - CHANGE: cross-channel register ping-pong. v8's per-iter critical path
//    vmcnt -> ds_read -> lgkmcnt(0) -> compute exposed the full LDS round-trip
//    (~120cy) per ~270cy of compute. Now: while computing ch q from registers,
//    ch q+1's ds_reads are in flight; lgkmcnt(0) lands AFTER the compute.
//    2 LDS slots/wave, 2 stages in flight (8 loads), s_waitcnt vmcnt(4) only.
//  - HARDENING (v9 crash suspect): drain vmcnt(0)+lgkmcnt(0) after the loop so
//    NO global_load_lds is outstanding at s_endpgm (LDS dealloc vs in-flight
//    DMA = undefined). v9's other change (1-wave blocks) is REVERTED: 192-thr
//    blocks keep the 3 sibling waves' f1 loads sharing L1 (FETCH 132MB proven).
// Kept: wave g owns di in {3g-4..3g-2} (f1 reuse x3), wave-private LDS (no
// barriers anywhere), XCD-chunked swizzle, global_load_lds width-16 staging,
// trash-row uniform vmcnt bookkeeping, pre-zeroed invalid edge rows,
// DPP wave_shr/shl halo (bound_ctrl:0 zero-fill = free column padding).

#define CT 128
#define HH 128
#define WW 256
#define NK 81
#define HW ((size_t)HH * WW)

// lane l <- lane l-1 ; lane 0 <- 0   (DPP wave_shr:1, bound_ctrl:0)
__device__ __forceinline__ float halo_left(float x) {
    return __int_as_float(__builtin_amdgcn_update_dpp(
        0, __float_as_int(x), 0x138, 0xF, 0xF, true));
}
// lane l <- lane l+1 ; lane 63 <- 0  (DPP wave_shl:1, bound_ctrl:0)
__device__ __forceinline__ float halo_right(float x) {
    return __int_as_float(__builtin_amdgcn_update_dpp(
        0, __float_as_int(x), 0x130, 0xF, 0xF, true));
}

typedef const __attribute__((address_space(1))) void* gas_ptr;
typedef __attribute__((address_space(3))) void* las_ptr;

#define STG(gp, dst) \
    __builtin_amdgcn_global_load_lds((gas_ptr)(gp), (las_ptr)(dst), 16, 0, 0);

// uniform 4-load stage of channel qq into this wave's slot ss; !real -> trash
#define STAGE(qq, ss, real)                                                   \
    {                                                                         \
        STG(p1  + (size_t)(qq) * HW,                                          \
            (real) ? (void*)&lds[g][ss][0][0] : (void*)&trash[0])             \
        STG(p2a + (size_t)(qq) * HW,                                          \
            ((real) && rv0) ? (void*)&lds[g][ss][1][0] : (void*)&trash[0])    \
        STG(p2b + (size_t)(qq) * HW,                                          \
            ((real) && rv1) ? (void*)&lds[g][ss][2][0] : (void*)&trash[0])    \
        STG(p2c + (size_t)(qq) * HW,                                          \
            ((real) && rv2) ? (void*)&lds[g][ss][3][0] : (void*)&trash[0])    \
    }

#define DSREAD(ss, F, Ra, Rb, Rc)                                             \
    F  = *(const float4*)&lds[g][ss][0][4 * l];                               \
    Ra = *(const float4*)&lds[g][ss][1][4 * l];                               \
    Rb = *(const float4*)&lds[g][ss][2][4 * l];                               \
    Rc = *(const float4*)&lds[g][ss][3][4 * l];

#define VMW(n) asm volatile("s_waitcnt vmcnt(" #n ")" ::: "memory")
#define LGW(n) asm volatile("s_waitcnt lgkmcnt(" #n ")" ::: "memory")
#define SB()   __builtin_amdgcn_sched_barrier(0)

// one f2 row's 9-dj contribution; j literal, acc never escapes
#define COMP_ROW(j, r)                                                  \
    {                                                                   \
        float w[12]; /* image cols 4l-4 .. 4l+7 */                      \
        w[0] = halo_left(r.x);  w[1] = halo_left(r.y);                  \
        w[2] = halo_left(r.z);  w[3] = halo_left(r.w);                  \
        w[4] = r.x; w[5] = r.y; w[6] = r.z; w[7] = r.w;                 \
        w[8] = halo_right(r.x);  w[9] = halo_right(r.y);                \
        w[10] = halo_right(r.z); w[11] = halo_right(r.w);               \
        _Pragma("unroll")                                               \
        for (int d = 0; d < 9; ++d) {                                   \
            acc[j][d][0] += fv0 * w[d];                                 \
            acc[j][d][1] += fv1 * w[d + 1];                             \
            acc[j][d][2] += fv2 * w[d + 2];                             \
            acc[j][d][3] += fv3 * w[d + 3];                             \
        }                                                               \
    }

#define COMPUTE(F, Ra, Rb, Rc)                                          \
    {                                                                   \
        const float fv0 = F.x, fv1 = F.y, fv2 = F.z, fv3 = F.w;         \
        COMP_ROW(0, Ra) COMP_ROW(1, Rb) COMP_ROW(2, Rc)                 \
    }

__global__ __launch_bounds__(192)
void corr_kernel(const float* __restrict__ f1, const float* __restrict__ f2,
                 float* __restrict__ out) {
    // lds[g] touched only by wave g -> no barriers. trash: write-only sink.
    __shared__ __align__(16) float lds[3][2][4][WW];  // 24,576 B
    __shared__ __align__(16) float trash[WW];         //  1,024 B

    const int l  = threadIdx.x & 63;       // lane: cols 4l..4l+3
    const int g  = threadIdx.x >> 6;       // 0..2: di group
    const int p  = blockIdx.x;
    const int L  = ((p & 7) << 7) | (p >> 3);  // XCD-chunked: XCD = batch
    const int b  = L >> 7;
    const int i0 = L & 127;

    const int  R0  = i0 - 4 + 3 * g;       // this wave's 3 f2 rows: R0..R0+2
    const bool rv0 = (unsigned)(R0)     < (unsigned)HH;
    const bool rv1 = (unsigned)(R0 + 1) < (unsigned)HH;
    const bool rv2 = (unsigned)(R0 + 2) < (unsigned)HH;

    const float* p1  = f1 + ((size_t)b * CT * HH + i0) * WW + 4 * l;
    const float* p2a = f2 + ((size_t)b * CT * HH + (rv0 ? R0     : 0)) * WW + 4 * l;
    const float* p2b = f2 + ((size_t)b * CT * HH + (rv1 ? R0 + 1 : 0)) * WW + 4 * l;
    const float* p2c = f2 + ((size_t)b * CT * HH + (rv2 ? R0 + 2 : 0)) * WW + 4 * l;

    // pre-zero invalid f2 rows in both slots; stages to them go to trash instead
    const float4 z4 = make_float4(0.f, 0.f, 0.f, 0.f);
    if (!rv0) { *(float4*)&lds[g][0][1][4*l] = z4; *(float4*)&lds[g][1][1][4*l] = z4; }
    if (!rv1) { *(float4*)&lds[g][0][2][4*l] = z4; *(float4*)&lds[g][1][2][4*l] = z4; }
    if (!rv2) { *(float4*)&lds[g][0][3][4*l] = z4; *(float4*)&lds[g][1][3][4*l] = z4; }

    float acc[3][9][4];
#pragma unroll
    for (int j = 0; j < 3; ++j)
#pragma unroll
        for (int d = 0; d < 9; ++d)
#pragma unroll
            for (int q = 0; q < 4; ++q) acc[j][d][q] = 0.f;

    float4 fA, rA0, rA1, rA2, fB, rB0, rB1, rB2;

    // prologue: fill both slots; A = ch0; re-stage slot0 with ch2
    STAGE(0, 0, true)
    STAGE(1, 1, true)                      // outstanding {0,1} = 8
    VMW(4);                                // stage(0) complete
    SB();
    DSREAD(0, fA, rA0, rA1, rA2)
    LGW(0);
    SB();
    STAGE(2, 0, true)                      // outstanding {1,2} = 8

    for (int q = 0; q < CT; q += 2) {
        // entry: A = ch q in regs; outstanding stages {q+1, q+2} = 8
        VMW(4);                            // stage(q+1) complete (issued 1 iter ago)
        SB();
        DSREAD(1, fB, rB0, rB1, rB2)       // issue reads for ch q+1 (slot 1)
        SB();
        COMPUTE(fA, rA0, rA1, rA2)         // ch q: ~270cy hides B's LDS latency
        LGW(0);                            // B in regs; slot1 free
        SB();
        { const int qq = q + 3; STAGE((qq < CT ? qq : CT - 1), 1, qq < CT) }
        // outstanding {q+2, q+3} = 8
        VMW(4);                            // stage(q+2) complete
        SB();
        DSREAD(0, fA, rA0, rA1, rA2)       // issue reads for ch q+2 (tail: junk)
        SB();
        COMPUTE(fB, rB0, rB1, rB2)         // ch q+1: hides A's LDS latency
        LGW(0);                            // A in regs; slot0 free
        SB();
        { const int qq = q + 4; STAGE((qq < CT ? qq : CT - 1), 0, qq < CT) }
        // outstanding {q+3, q+4} = 8 -> invariant holds
    }

    // drain: NOTHING outstanding at s_endpgm (v9 crash suspect: in-flight
    // LDS-DMA at workgroup teardown)
    VMW(0);
    LGW(0);
    SB();

    const float s = 1.0f / 128.0f;
#pragma unroll
    for (int j = 0; j < 3; ++j) {
        const int k = (3 * g + j) * 9;
#pragma unroll
        for (int d = 0; d < 9; ++d) {
            float* op = out + ((size_t)(b * NK + k + d) * HH + i0) * WW + 4 * l;
            *(float4*)op = make_float4(acc[j][d][0] * s, acc[j][d][1] * s,
                                       acc[j][d][2] * s, acc[j][d][3] * s);
        }
    }
}

extern "C" void kernel_launch(void* const* d_in, const int* in_sizes, int n_in,
                              void* d_out, int out_size, void* d_ws, size_t ws_size,
                              hipStream_t stream) {
    const float* f1 = (const float*)d_in[0];
    const float* f2 = (const float*)d_in[1];
    float* out = (float*)d_out;
    dim3 grid(1024);       // one block per (b, i0); swizzled so XCD = batch
    dim3 block(192);       // 3 waves, 3 di each; wave-private LDS, no barriers
    hipLaunchKernelGGL(corr_kernel, grid, block, 0, stream, f1, f2, out);
}

// Round 8
// 365.854 us; speedup vs baseline: 1.0440x; 1.0440x over previous
//
#include <hip/hip_runtime.h>

// Correlation: out[b,(di+4)*9+(dj+4),i,j] = (1/128) * sum_c f1[b,c,i,j]*f2[b,c,i+di,j+dj]
// B=8 C=128 H=128 W=256, di,dj in [-4,4], f2 zero-padded.
//
// v11 = v10 + ONE change: restore DEPTH-3 staging (v10 post-mortem: the 2-slot
// ping-pong silently cut the async pipeline depth 3->2; vmcnt(4) lead ~600cy <
// 900cy HBM latency -> ~300cy exposed per channel, 160->199us regression, and
// +28 VGPR dropped occupancy 10->5 waves/CU). Now BOTH stall sources are off
// the critical path at once:
//  - 3 LDS slots/wave, 3 stages in flight (12 loads), waits vmcnt(8) ONLY:
//    load->use lead = 3 channel-periods (~1200cy) > HBM 900cy.  [v8's depth]
//  - register ping-pong: ds_reads for ch q+1 issue before COMPUTE(ch q);
//    lgkmcnt(0) lands after -> LDS round-trip hidden.            [v10's overlap]
// Slot index cycles mod 3 at runtime (wave-uniform int -> pure address math;
// NO pointer/register arrays -> nothing can spill). Everything else identical
// to v10: 192-thr blocks (3 waves, wave-private LDS, f1 L1-shared x3), XCD
// swizzle, width-16 global_load_lds, trash-row uniform vmcnt bookkeeping,
// pre-zeroed invalid edge rows, DPP halo, full vmcnt/lgkmcnt drain pre-endpgm.

#define CT 128
#define HH 128
#define WW 256
#define NK 81
#define HW ((size_t)HH * WW)

// lane l <- lane l-1 ; lane 0 <- 0   (DPP wave_shr:1, bound_ctrl:0)
__device__ __forceinline__ float halo_left(float x) {
    return __int_as_float(__builtin_amdgcn_update_dpp(
        0, __float_as_int(x), 0x138, 0xF, 0xF, true));
}
// lane l <- lane l+1 ; lane 63 <- 0  (DPP wave_shl:1, bound_ctrl:0)
__device__ __forceinline__ float halo_right(float x) {
    return __int_as_float(__builtin_amdgcn_update_dpp(
        0, __float_as_int(x), 0x130, 0xF, 0xF, true));
}

typedef const __attribute__((address_space(1))) void* gas_ptr;
typedef __attribute__((address_space(3))) void* las_ptr;

#define STG(gp, dst) \
    __builtin_amdgcn_global_load_lds((gas_ptr)(gp), (las_ptr)(dst), 16, 0, 0);

// uniform 4-load stage of channel qq into slot ss (runtime, wave-uniform)
#define STAGE(qq, ss, real)                                                   \
    {                                                                         \
        float* _dp = ldsg + (ss) * (4 * WW);                                  \
        STG(p1  + (size_t)(qq) * HW, (real) ? _dp : &trash[0])                \
        STG(p2a + (size_t)(qq) * HW,                                          \
            ((real) && rv0) ? _dp + WW : &trash[0])                           \
        STG(p2b + (size_t)(qq) * HW,                                          \
            ((real) && rv1) ? _dp + 2 * WW : &trash[0])                       \
        STG(p2c + (size_t)(qq) * HW,                                          \
            ((real) && rv2) ? _dp + 3 * WW : &trash[0])                       \
    }

#define DSREAD(ss, F, Ra, Rb, Rc)                                             \
    {                                                                         \
        const float* _sp = ldsg + (ss) * (4 * WW) + 4 * l;                    \
        F  = *(const float4*)(_sp);                                           \
        Ra = *(const float4*)(_sp + WW);                                      \
        Rb = *(const float4*)(_sp + 2 * WW);                                  \
        Rc = *(const float4*)(_sp + 3 * WW);                                  \
    }

#define VMW(n) asm volatile("s_waitcnt vmcnt(" #n ")" ::: "memory")
#define LGW(n) asm volatile("s_waitcnt lgkmcnt(" #n ")" ::: "memory")
#define SB()   __builtin_amdgcn_sched_barrier(0)

// one f2 row's 9-dj contribution; j literal, acc never escapes
#define COMP_ROW(j, r)                                                  \
    {                                                                   \
        float w[12]; /* image cols 4l-4 .. 4l+7 */                      \
        w[0] = halo_left(r.x);  w[1] = halo_left(r.y);                  \
        w[2] = halo_left(r.z);  w[3] = halo_left(r.w);                  \
        w[4] = r.x; w[5] = r.y; w[6] = r.z; w[7] = r.w;                 \
        w[8] = halo_right(r.x);  w[9] = halo_right(r.y);                \
        w[10] = halo_right(r.z); w[11] = halo_right(r.w);               \
        _Pragma("unroll")                                               \
        for (int d = 0; d < 9; ++d) {                                   \
            acc[j][d][0] += fv0 * w[d];                                 \
            acc[j][d][1] += fv1 * w[d + 1];                             \
            acc[j][d][2] += fv2 * w[d + 2];                             \
            acc[j][d][3] += fv3 * w[d + 3];                             \
        }                                                               \
    }

#define COMPUTE(F, Ra, Rb, Rc)                                          \
    {                                                                   \
        const float fv0 = F.x, fv1 = F.y, fv2 = F.z, fv3 = F.w;         \
        COMP_ROW(0, Ra) COMP_ROW(1, Rb) COMP_ROW(2, Rc)                 \
    }

__global__ __launch_bounds__(192)
void corr_kernel(const float* __restrict__ f1, const float* __restrict__ f2,
                 float* __restrict__ out) {
    // lds[g] touched only by wave g -> no barriers. trash: write-only sink.
    __shared__ __align__(16) float lds[3][3][4][WW];  // 36,864 B
    __shared__ __align__(16) float trash[WW];         //  1,024 B

    const int l  = threadIdx.x & 63;       // lane: cols 4l..4l+3
    const int g  = threadIdx.x >> 6;       // 0..2: di group
    const int p  = blockIdx.x;
    const int L  = ((p & 7) << 7) | (p >> 3);  // XCD-chunked: XCD = batch
    const int b  = L >> 7;
    const int i0 = L & 127;

    float* ldsg = &lds[g][0][0][0];        // this wave's private region

    const int  R0  = i0 - 4 + 3 * g;       // this wave's 3 f2 rows: R0..R0+2
    const bool rv0 = (unsigned)(R0)     < (unsigned)HH;
    const bool rv1 = (unsigned)(R0 + 1) < (unsigned)HH;
    const bool rv2 = (unsigned)(R0 + 2) < (unsigned)HH;

    const float* p1  = f1 + ((size_t)b * CT * HH + i0) * WW + 4 * l;
    const float* p2a = f2 + ((size_t)b * CT * HH + (rv0 ? R0     : 0)) * WW + 4 * l;
    const float* p2b = f2 + ((size_t)b * CT * HH + (rv1 ? R0 + 1 : 0)) * WW + 4 * l;
    const float* p2c = f2 + ((size_t)b * CT * HH + (rv2 ? R0 + 2 : 0)) * WW + 4 * l;

    // pre-zero invalid f2 rows in all 3 slots; stages to them go to trash
    const float4 z4 = make_float4(0.f, 0.f, 0.f, 0.f);
#pragma unroll
    for (int ss = 0; ss < 3; ++ss) {
        if (!rv0) *(float4*)(ldsg + ss * (4 * WW) + WW     + 4 * l) = z4;
        if (!rv1) *(float4*)(ldsg + ss * (4 * WW) + 2 * WW + 4 * l) = z4;
        if (!rv2) *(float4*)(ldsg + ss * (4 * WW) + 3 * WW + 4 * l) = z4;
    }

    float acc[3][9][4];
#pragma unroll
    for (int j = 0; j < 3; ++j)
#pragma unroll
        for (int d = 0; d < 9; ++d)
#pragma unroll
            for (int q = 0; q < 4; ++q) acc[j][d][q] = 0.f;

    float4 fA, rA0, rA1, rA2, fB, rB0, rB1, rB2;

    // prologue: fill ring 3 deep; A = ch0; re-stage slot0 with ch3
    STAGE(0, 0, true)
    STAGE(1, 1, true)
    STAGE(2, 2, true)                      // outstanding {0,1,2} = 12
    VMW(8);                                // stage(0) complete
    SB();
    DSREAD(0, fA, rA0, rA1, rA2)
    LGW(0);
    SB();
    STAGE(3, 0, true)                      // outstanding {1,2,3} = 12

    int sB = 1, sA2 = 2;                   // slots of ch q+1 / ch q+2 (mod 3)
    for (int q = 0; q < CT; q += 2) {
        // entry: A = ch q; outstanding {q+1,q+2,q+3} = 12
        VMW(8);                            // stage(q+1) done (issued 3 periods ago)
        SB();
        DSREAD(sB, fB, rB0, rB1, rB2)      // issue reads for ch q+1
        SB();
        COMPUTE(fA, rA0, rA1, rA2)         // ch q (~300cy) hides B's LDS latency
        LGW(0);                            // B ready; slot sB free
        SB();
        { const int qq = q + 4; STAGE((qq < CT ? qq : CT - 1), sB, qq < CT) }
        // outstanding {q+2,q+3,q+4} = 12
        VMW(8);                            // stage(q+2) done
        SB();
        DSREAD(sA2, fA, rA0, rA1, rA2)     // issue reads for ch q+2 (tail: junk)
        SB();
        COMPUTE(fB, rB0, rB1, rB2)         // ch q+1 hides A's LDS latency
        LGW(0);                            // A ready; slot sA2 free
        SB();
        { const int qq = q + 5; STAGE((qq < CT ? qq : CT - 1), sA2, qq < CT) }
        // outstanding {q+3,q+4,q+5} = 12 -> invariant holds
        sB += 2;  if (sB >= 3)  sB -= 3;   // (q+1)%3 for next q
        sA2 += 2; if (sA2 >= 3) sA2 -= 3;  // (q+2)%3 for next q
    }

    // drain: NOTHING outstanding at s_endpgm (LDS dealloc vs in-flight DMA)
    VMW(0);
    LGW(0);
    SB();

    const float s = 1.0f / 128.0f;
#pragma unroll
    for (int j = 0; j < 3; ++j) {
        const int k = (3 * g + j) * 9;
#pragma unroll
        for (int d = 0; d < 9; ++d) {
            float* op = out + ((size_t)(b * NK + k + d) * HH + i0) * WW + 4 * l;
            *(float4*)op = make_float4(acc[j][d][0] * s, acc[j][d][1] * s,
                                       acc[j][d][2] * s, acc[j][d][3] * s);
        }
    }
}

extern "C" void kernel_launch(void* const* d_in, const int* in_sizes, int n_in,
                              void* d_out, int out_size, void* d_ws, size_t ws_size,
                              hipStream_t stream) {
    const float* f1 = (const float*)d_in[0];
    const float* f2 = (const float*)d_in[1];
    float* out = (float*)d_out;
    dim3 grid(1024);       // one block per (b, i0); swizzled so XCD = batch
    dim3 block(192);       // 3 waves, 3 di each; wave-private LDS, no barriers
    hipLaunchKernelGGL(corr_kernel, grid, block, 0, stream, f1, f2, out);
}